// Round 1
// 471.776 us; speedup vs baseline: 1.0292x; 1.0292x over previous
//
#include <hip/hip_runtime.h>

typedef unsigned short u16;
typedef unsigned int u32;
typedef __attribute__((ext_vector_type(8))) short s16x8;
typedef __attribute__((ext_vector_type(4))) float f32x4;

#define GAS __attribute__((address_space(1)))
#define LAS __attribute__((address_space(3)))

// ---- constants ----
#define BB 4
#define LL 8192
#define DD 1024
#define NH 16
#define HD 64
#define MROWS (BB * LL)          // 32768
#define NWBT 2064                // 1024 Q + 1024 K + 16 WvS rows

__device__ __forceinline__ u16 f2bf(float f) {
  u32 u = __builtin_bit_cast(u32, f);
  u32 r = (u + 0x7FFFu + ((u >> 16) & 1u)) >> 16;
  return (u16)r;
}
__device__ __forceinline__ float bf2f(u32 lo) {
  return __builtin_bit_cast(float, lo << 16);
}

__device__ __forceinline__ void async16(const void* g, void* l) {
  __builtin_amdgcn_global_load_lds((const GAS u32*)g, (LAS u32*)l, 16, 0, 0);
}

// mask encoding modes: 0 = int32, 1 = float32, 2 = uint8
__device__ __forceinline__ bool get_mask(const void* mp, int row, int mode) {
  if (mode == 2) return ((const unsigned char*)mp)[row] != 0;
  if (mode == 1) return ((const float*)mp)[row] != 0.f;
  return ((const int*)mp)[row] != 0;
}

// Classify mask dtype by inspecting first 8192 32-bit words.
__global__ void detect_mask(const u32* __restrict__ m, int* __restrict__ flag) {
  int i = blockIdx.x * 256 + threadIdx.x;  // 8192 threads
  u32 v = m[i];
  int f = 0;
  if (v == 0x3F800000u) f = 1;       // looks like float 1.0
  else if (v > 1u) f = 2;            // packed bytes -> uint8
  if (f) atomicMax(flag, f);
}

// Build WbT[n][k] = W{q,k}[k][n mod 1024] as bf16 (transposed, 32x32 LDS tiles)
__global__ void build_wbt(const float* __restrict__ Wq, const float* __restrict__ Wk,
                          u16* __restrict__ WbT) {
  __shared__ float t[32][33];
  const int n0 = blockIdx.x * 32;  // 0..2047
  const int k0 = blockIdx.y * 32;  // 0..1023
  const float* W = (n0 >> 10) == 0 ? Wq : Wk;
  const int nloc = n0 & 1023;
  const int tx = threadIdx.x, ty = threadIdx.y;  // 32 x 8
#pragma unroll
  for (int j = 0; j < 32; j += 8)
    t[ty + j][tx] = W[(size_t)(k0 + ty + j) * DD + nloc + tx];
  __syncthreads();
#pragma unroll
  for (int j = 0; j < 32; j += 8)
    WbT[(size_t)(n0 + ty + j) * DD + k0 + tx] = f2bf(t[tx][ty + j]);
}

// WbT rows 2048..2063: WvS[h][k] = sum_{j<64} Wv[k][h*64+j]  (bf16)
__global__ void build_wvs(const float* __restrict__ Wv, u16* __restrict__ WbT) {
  int i = blockIdx.x * 256 + threadIdx.x;  // 16384: k = i>>4, h = i&15
  int k = i >> 4, h = i & 15;
  float s = 0.f;
  const float* p = Wv + (size_t)k * DD + h * HD;
#pragma unroll 8
  for (int j = 0; j < 64; ++j) s += p[j];
  WbT[(size_t)(2048 + h) * DD + k] = f2bf(s);
}

// bcat[0..1023]=bq, [1024..2047]=bk, [2048+h]=sum_{j<64} bv[h*64+j]
__global__ void build_bcat(const float* __restrict__ bq, const float* __restrict__ bk,
                           const float* __restrict__ bv, float* __restrict__ bcat) {
  int i = blockIdx.x * 256 + threadIdx.x;
  if (i < 1024) bcat[i] = bq[i];
  else if (i < 2048) bcat[i] = bk[i - 1024];
  else if (i < 2064) {
    float s = 0.f;
    const float* p = bv + (i - 2048) * HD;
#pragma unroll 8
    for (int j = 0; j < 64; ++j) s += p[j];
    bcat[i] = s;
  }
}

// Fused query fp32->bf16 conversion + sV GEMM.
// Each block: 128 rows. Streams query tiles fp32 -> bf16 (global qb write +
// swizzled LDS), and accumulates sV[row][h] = qb[row]·WvS[h] + bvS[h] via a
// skinny 128x16 MFMA against the WvS panel staged once in LDS (32 KB).
// Masked rows -> sV = 0.
__global__ __launch_bounds__(256) void prep_q(
    const float* __restrict__ query, const u16* __restrict__ WbT,
    const float* __restrict__ bcat, const void* __restrict__ maskp,
    const int* __restrict__ mmode,
    u16* __restrict__ qb, float* __restrict__ sV) {
  __shared__ u16 ldsW[16 * 1024];  // 32 KB, chunk-swizzled WvS panel
  __shared__ u16 ldsA[128 * 64];   // 16 KB, per-step A tile
  const int tid = threadIdx.x;
  const int lane = tid & 63;
  const int w = tid >> 6;
  const int row0 = blockIdx.x * 128;

  // stage WvS (WbT rows 2048..2063): global chunk c of row h at slot c^(h&7)
  {
    const int h = tid & 15;
    const int cb = tid >> 4;  // 0..15
#pragma unroll
    for (int j = 0; j < 8; ++j) {
      const int c = cb * 8 + j;  // global 8-elem chunk 0..127
      s16x8 v = *(const s16x8*)(WbT + (size_t)(2048 + h) * DD + c * 8);
      *(s16x8*)(ldsW + h * 1024 + (c ^ (h & 7)) * 8) = v;
    }
  }

  const int r_l = tid >> 3;   // 0..31: row within 32-row stripe
  const int slot = tid & 7;   // LDS slot this lane fills
  f32x4 acc[2] = {};

  for (int k0 = 0; k0 < DD; k0 += 64) {
    __syncthreads();
#pragma unroll
    for (int i = 0; i < 4; ++i) {
      const int rl = i * 32 + r_l;
      const int seg = slot ^ (rl & 7);  // global k-segment fetched (swizzle)
      const float* gp = query + (size_t)(row0 + rl) * DD + k0 + seg * 8;
      float4 v0 = *(const float4*)gp;
      float4 v1 = *(const float4*)(gp + 4);
      s16x8 o;
      o[0] = (short)f2bf(v0.x); o[1] = (short)f2bf(v0.y);
      o[2] = (short)f2bf(v0.z); o[3] = (short)f2bf(v0.w);
      o[4] = (short)f2bf(v1.x); o[5] = (short)f2bf(v1.y);
      o[6] = (short)f2bf(v1.z); o[7] = (short)f2bf(v1.w);
      *(s16x8*)(qb + (size_t)(row0 + rl) * DD + k0 + seg * 8) = o;
      *(s16x8*)(ldsA + rl * 64 + slot * 8) = o;
    }
    __syncthreads();
#pragma unroll
    for (int kk = 0; kk < 2; ++kk) {
      const int segk = kk * 4 + (lane >> 4);
      const int hh = lane & 15;
      const int cc = (k0 >> 3) + segk;  // global 8-elem chunk index
      s16x8 bfr = *(const s16x8*)(ldsW + hh * 1024 + (cc ^ (hh & 7)) * 8);
#pragma unroll
      for (int mi = 0; mi < 2; ++mi) {
        const int r = w * 32 + mi * 16 + hh;
        s16x8 af = *(const s16x8*)(ldsA + r * 64 + ((segk ^ (r & 7))) * 8);
        acc[mi] = __builtin_amdgcn_mfma_f32_16x16x32_bf16(af, bfr, acc[mi], 0, 0, 0);
      }
    }
  }

  const int mode = *mmode;
  const int lanec = lane & 15, laneq = lane >> 4;
#pragma unroll
  for (int mi = 0; mi < 2; ++mi)
#pragma unroll
    for (int r = 0; r < 4; ++r) {
      const int row = row0 + w * 32 + mi * 16 + laneq * 4 + r;
      const bool msk = get_mask(maskp, row, mode);
      float v = acc[mi][r] + bcat[2048 + lanec];
      sV[(size_t)row * NH + lanec] = msk ? 0.f : v;
    }
}

// Fused projection GEMM: C[m][n] = sum_k qb[m][k] * WbT[n][k].
// phase 1 (runs FIRST, grid.y = 8): K col-tiles (col0 = 1024 + y*128) -> phiK
//   computed in registers, multiplied by sV and row-reduced; partial kv_sum
//   atomicAdd'ed. phiK never touches memory.
// phase 0 (runs SECOND, grid.y = 8): Q col-tiles -> out = phiQ * kv_sum
//   written fp32 directly (finalize fused; phiQ never materialized).
// LDS XOR-swizzle: row r's k-segment `seg` lives at slot seg^(r&7) -> the
// 16-lane fragment ds_read_b128 spreads over 8 slots (2-way = free).
__global__ __launch_bounds__(256) void gemm_qkv(
    const u16* __restrict__ qb, const u16* __restrict__ WbT,
    const float* __restrict__ bcat, const void* __restrict__ maskp,
    const int* __restrict__ mmode,
    const float* __restrict__ sV, float* __restrict__ kv,
    float* __restrict__ out, int phase) {
  __shared__ u16 ldsA[128 * 64];
  __shared__ u16 ldsB[128 * 64];
  const int tid = threadIdx.x;
  const int lane = tid & 63;
  const int w = tid >> 6;
  const int wm = w & 1, wn = w >> 1;
  const int row0 = blockIdx.x * 128;
  const int cy = blockIdx.y;
  const int col0 = phase == 0 ? cy * 128 : 1024 + cy * 128;

  f32x4 acc[4][4] = {};

  const int r_l = tid >> 3;            // 0..31: row within 32-row stripe
  const int slot = tid & 7;            // LDS slot this lane fills
  const int seg = slot ^ (r_l & 7);    // global k-segment it fetches (swizzle)
  const u16* gA = qb + (size_t)(row0 + r_l) * DD + seg * 8;
  const u16* gB = WbT + (size_t)(col0 + r_l) * DD + seg * 8;

  for (int k0 = 0; k0 < DD; k0 += 64) {
    __syncthreads();
#pragma unroll
    for (int i = 0; i < 4; ++i) {
      async16(gA + (size_t)i * 32 * DD + k0, ldsA + (i * 256 + tid) * 8);
      async16(gB + (size_t)i * 32 * DD + k0, ldsB + (i * 256 + tid) * 8);
    }
    __syncthreads();
#pragma unroll
    for (int kk = 0; kk < 2; ++kk) {
      s16x8 af[4], bfr[4];
      const int segk = kk * 4 + (lane >> 4);  // k-segment index within stage
#pragma unroll
      for (int mi = 0; mi < 4; ++mi) {
        const int r = wm * 64 + mi * 16 + (lane & 15);
        af[mi] = *(const s16x8*)(ldsA + r * 64 + (segk ^ (r & 7)) * 8);
      }
#pragma unroll
      for (int ni = 0; ni < 4; ++ni) {
        const int r = wn * 64 + ni * 16 + (lane & 15);
        bfr[ni] = *(const s16x8*)(ldsB + r * 64 + (segk ^ (r & 7)) * 8);
      }
#pragma unroll
      for (int mi = 0; mi < 4; ++mi)
#pragma unroll
        for (int ni = 0; ni < 4; ++ni)
          acc[mi][ni] = __builtin_amdgcn_mfma_f32_16x16x32_bf16(af[mi], bfr[ni], acc[mi][ni], 0, 0, 0);
    }
  }

  const int mode = *mmode;
  const int lanec = lane & 15, laneq = lane >> 4;
  const int wcol0 = col0 + wn * 64;  // wave spans exactly one 64-col group
  const int b = row0 >> 13;          // batch (rows never cross b)

  if (phase == 1) {
    // K section with fused kv_sum reduction
    const int n = (wcol0 - 1024) >> 6;   // head, uniform per wave
    float pc[4] = {0.f, 0.f, 0.f, 0.f};
#pragma unroll
    for (int mi = 0; mi < 4; ++mi) {
#pragma unroll
      for (int r = 0; r < 4; ++r) {
        const int row = row0 + wm * 64 + mi * 16 + laneq * 4 + r;
        const bool msk = get_mask(maskp, row, mode);
        if (!msk) {
          const float sv = sV[(size_t)row * NH + n];
#pragma unroll
          for (int ni = 0; ni < 4; ++ni) {
            const int col = wcol0 + ni * 16 + lanec;
            float v = acc[mi][ni][r] + bcat[col];
            float phi = v > 0.f ? v + 1.f : __expf(v);
            pc[ni] += phi * sv;
          }
        }
      }
    }
#pragma unroll
    for (int ni = 0; ni < 4; ++ni) {
      pc[ni] += __shfl_xor(pc[ni], 16);
      pc[ni] += __shfl_xor(pc[ni], 32);
    }
    if (laneq == 0) {
#pragma unroll
      for (int ni = 0; ni < 4; ++ni) {
        const int colk = wcol0 - 1024 + ni * 16 + lanec;  // 0..1023
        atomicAdd(&kv[b * DD + colk], pc[ni]);
      }
    }
  } else {
    // Q section -> out = phi * kv_sum (finalize fused)
    float kvv[4];
#pragma unroll
    for (int ni = 0; ni < 4; ++ni)
      kvv[ni] = kv[b * DD + wcol0 + ni * 16 + lanec];
#pragma unroll
    for (int mi = 0; mi < 4; ++mi) {
#pragma unroll
      for (int r = 0; r < 4; ++r) {
        const int row = row0 + wm * 64 + mi * 16 + laneq * 4 + r;
#pragma unroll
        for (int ni = 0; ni < 4; ++ni) {
          const int col = wcol0 + ni * 16 + lanec;
          float v = acc[mi][ni][r] + bcat[col];
          float phi = v > 0.f ? v + 1.f : __expf(v);
          out[(size_t)row * DD + col] = phi * kvv[ni];
        }
      }
    }
  }
}

extern "C" void kernel_launch(void* const* d_in, const int* in_sizes, int n_in,
                              void* d_out, int out_size, void* d_ws, size_t ws_size,
                              hipStream_t stream) {
  const float* query = (const float*)d_in[0];
  const void* maskp = d_in[1];
  const float* Wq = (const float*)d_in[2];
  const float* bq = (const float*)d_in[3];
  const float* Wk = (const float*)d_in[4];
  const float* bk = (const float*)d_in[5];
  const float* Wv = (const float*)d_in[6];
  const float* bv = (const float*)d_in[7];
  float* out = (float*)d_out;

  char* ws = (char*)d_ws;
  u16* qb = (u16*)ws;            ws += (size_t)MROWS * DD * 2;      // 64 MB
  u16* WbT = (u16*)ws;           ws += (size_t)NWBT * DD * 2;       // ~4.2 MB
  float* sV = (float*)ws;        ws += (size_t)MROWS * NH * 4;      // 2 MB
  float* bcat = (float*)ws;      ws += (size_t)NWBT * 4;
  float* kv = (float*)ws;        ws += (size_t)BB * DD * 4;         // 16 KB
  int* mflag = (int*)ws;         ws += 256;

  // zero kv_sum + mask-mode flag
  hipMemsetAsync(kv, 0, (size_t)BB * DD * 4 + 256, stream);

  detect_mask<<<32, 256, 0, stream>>>((const u32*)maskp, mflag);
  build_wbt<<<dim3(2048 / 32, DD / 32), dim3(32, 8), 0, stream>>>(Wq, Wk, WbT);
  build_wvs<<<64, 256, 0, stream>>>(Wv, WbT);
  build_bcat<<<(NWBT + 255) / 256, 256, 0, stream>>>(bq, bk, bv, bcat);
  // fused cvt + sV
  prep_q<<<MROWS / 128, 256, 0, stream>>>(query, WbT, bcat, maskp, mflag, qb, sV);
  // K phase first: kv_sum (fused reduction, no phiK materialization)
  gemm_qkv<<<dim3(MROWS / 128, 8), 256, 0, stream>>>(
      qb, WbT, bcat, maskp, mflag, sV, kv, out, 1);
  // Q phase: out = phiQ * kv_sum (finalize fused, no phiQ materialization)
  gemm_qkv<<<dim3(MROWS / 128, 8), 256, 0, stream>>>(
      qb, WbT, bcat, maskp, mflag, sV, kv, out, 0);
}

// Round 2
// 429.378 us; speedup vs baseline: 1.1308x; 1.0987x over previous
//
#include <hip/hip_runtime.h>

typedef unsigned short u16;
typedef unsigned int u32;
typedef __attribute__((ext_vector_type(8))) short s16x8;
typedef __attribute__((ext_vector_type(4))) float f32x4;

#define GAS __attribute__((address_space(1)))
#define LAS __attribute__((address_space(3)))

// ---- constants ----
#define BB 4
#define LL 8192
#define DD 1024
#define NH 16
#define HD 64
#define MROWS (BB * LL)          // 32768
#define NWBT 2064                // 1024 Q + 1024 K + 16 WvS rows

__device__ __forceinline__ u16 f2bf(float f) {
  u32 u = __builtin_bit_cast(u32, f);
  u32 r = (u + 0x7FFFu + ((u >> 16) & 1u)) >> 16;
  return (u16)r;
}
__device__ __forceinline__ float bf2f(u32 lo) {
  return __builtin_bit_cast(float, lo << 16);
}

__device__ __forceinline__ void async16(const void* g, void* l) {
  __builtin_amdgcn_global_load_lds((const GAS u32*)g, (LAS u32*)l, 16, 0, 0);
}

// mask encoding modes: 0 = int32, 1 = float32, 2 = uint8
__device__ __forceinline__ bool get_mask(const void* mp, int row, int mode) {
  if (mode == 2) return ((const unsigned char*)mp)[row] != 0;
  if (mode == 1) return ((const float*)mp)[row] != 0.f;
  return ((const int*)mp)[row] != 0;
}

// Classify mask dtype by inspecting first 8192 32-bit words.
__global__ void detect_mask(const u32* __restrict__ m, int* __restrict__ flag) {
  int i = blockIdx.x * 256 + threadIdx.x;  // 8192 threads
  u32 v = m[i];
  int f = 0;
  if (v == 0x3F800000u) f = 1;       // looks like float 1.0
  else if (v > 1u) f = 2;            // packed bytes -> uint8
  if (f) atomicMax(flag, f);
}

// Build WbT[n][k] = W{q,k}[k][n mod 1024] as bf16 (transposed, 32x32 LDS tiles)
__global__ void build_wbt(const float* __restrict__ Wq, const float* __restrict__ Wk,
                          u16* __restrict__ WbT) {
  __shared__ float t[32][33];
  const int n0 = blockIdx.x * 32;  // 0..2047
  const int k0 = blockIdx.y * 32;  // 0..1023
  const float* W = (n0 >> 10) == 0 ? Wq : Wk;
  const int nloc = n0 & 1023;
  const int tx = threadIdx.x, ty = threadIdx.y;  // 32 x 8
#pragma unroll
  for (int j = 0; j < 32; j += 8)
    t[ty + j][tx] = W[(size_t)(k0 + ty + j) * DD + nloc + tx];
  __syncthreads();
#pragma unroll
  for (int j = 0; j < 32; j += 8)
    WbT[(size_t)(n0 + ty + j) * DD + k0 + tx] = f2bf(t[tx][ty + j]);
}

// WbT rows 2048..2063: WvS[h][k] = sum_{j<64} Wv[k][h*64+j]  (bf16)
__global__ void build_wvs(const float* __restrict__ Wv, u16* __restrict__ WbT) {
  int i = blockIdx.x * 256 + threadIdx.x;  // 16384: k = i>>4, h = i&15
  int k = i >> 4, h = i & 15;
  float s = 0.f;
  const float* p = Wv + (size_t)k * DD + h * HD;
#pragma unroll 8
  for (int j = 0; j < 64; ++j) s += p[j];
  WbT[(size_t)(2048 + h) * DD + k] = f2bf(s);
}

// bcat[0..1023]=bq, [1024..2047]=bk, [2048+h]=sum_{j<64} bv[h*64+j]
__global__ void build_bcat(const float* __restrict__ bq, const float* __restrict__ bk,
                           const float* __restrict__ bv, float* __restrict__ bcat) {
  int i = blockIdx.x * 256 + threadIdx.x;
  if (i < 1024) bcat[i] = bq[i];
  else if (i < 2048) bcat[i] = bk[i - 1024];
  else if (i < 2064) {
    float s = 0.f;
    const float* p = bv + (i - 2048) * HD;
#pragma unroll 8
    for (int j = 0; j < 64; ++j) s += p[j];
    bcat[i] = s;
  }
}

// Fused query fp32->bf16 conversion + sV GEMM (unchanged from round 1).
__global__ __launch_bounds__(256) void prep_q(
    const float* __restrict__ query, const u16* __restrict__ WbT,
    const float* __restrict__ bcat, const void* __restrict__ maskp,
    const int* __restrict__ mmode,
    u16* __restrict__ qb, float* __restrict__ sV) {
  __shared__ u16 ldsW[16 * 1024];  // 32 KB, chunk-swizzled WvS panel
  __shared__ u16 ldsA[128 * 64];   // 16 KB, per-step A tile
  const int tid = threadIdx.x;
  const int lane = tid & 63;
  const int w = tid >> 6;
  const int row0 = blockIdx.x * 128;

  {
    const int h = tid & 15;
    const int cb = tid >> 4;  // 0..15
#pragma unroll
    for (int j = 0; j < 8; ++j) {
      const int c = cb * 8 + j;  // global 8-elem chunk 0..127
      s16x8 v = *(const s16x8*)(WbT + (size_t)(2048 + h) * DD + c * 8);
      *(s16x8*)(ldsW + h * 1024 + (c ^ (h & 7)) * 8) = v;
    }
  }

  const int r_l = tid >> 3;   // 0..31: row within 32-row stripe
  const int slot = tid & 7;   // LDS slot this lane fills
  f32x4 acc[2] = {};

  for (int k0 = 0; k0 < DD; k0 += 64) {
    __syncthreads();
#pragma unroll
    for (int i = 0; i < 4; ++i) {
      const int rl = i * 32 + r_l;
      const int seg = slot ^ (rl & 7);  // global k-segment fetched (swizzle)
      const float* gp = query + (size_t)(row0 + rl) * DD + k0 + seg * 8;
      float4 v0 = *(const float4*)gp;
      float4 v1 = *(const float4*)(gp + 4);
      s16x8 o;
      o[0] = (short)f2bf(v0.x); o[1] = (short)f2bf(v0.y);
      o[2] = (short)f2bf(v0.z); o[3] = (short)f2bf(v0.w);
      o[4] = (short)f2bf(v1.x); o[5] = (short)f2bf(v1.y);
      o[6] = (short)f2bf(v1.z); o[7] = (short)f2bf(v1.w);
      *(s16x8*)(qb + (size_t)(row0 + rl) * DD + k0 + seg * 8) = o;
      *(s16x8*)(ldsA + rl * 64 + slot * 8) = o;
    }
    __syncthreads();
#pragma unroll
    for (int kk = 0; kk < 2; ++kk) {
      const int segk = kk * 4 + (lane >> 4);
      const int hh = lane & 15;
      const int cc = (k0 >> 3) + segk;  // global 8-elem chunk index
      s16x8 bfr = *(const s16x8*)(ldsW + hh * 1024 + (cc ^ (hh & 7)) * 8);
#pragma unroll
      for (int mi = 0; mi < 2; ++mi) {
        const int r = w * 32 + mi * 16 + hh;
        s16x8 af = *(const s16x8*)(ldsA + r * 64 + ((segk ^ (r & 7))) * 8);
        acc[mi] = __builtin_amdgcn_mfma_f32_16x16x32_bf16(af, bfr, acc[mi], 0, 0, 0);
      }
    }
  }

  const int mode = *mmode;
  const int lanec = lane & 15, laneq = lane >> 4;
#pragma unroll
  for (int mi = 0; mi < 2; ++mi)
#pragma unroll
    for (int r = 0; r < 4; ++r) {
      const int row = row0 + w * 32 + mi * 16 + laneq * 4 + r;
      const bool msk = get_mask(maskp, row, mode);
      float v = acc[mi][r] + bcat[2048 + lanec];
      sV[(size_t)row * NH + lanec] = msk ? 0.f : v;
    }
}

// ---------------------------------------------------------------------------
// 256x256-tile, 8-phase, counted-vmcnt projection GEMM (T1+T2+T3+T4+T5).
// C[m][n] = sum_k qb[m][k] * WbT[n][k].  BK=64, 2 K-tiles/iter, 8 waves
// (2M x 4N), per-wave output 128x64 (acc[8][4] 16x16 frags).
// LDS 128 KiB = 2 dbuf x (A 256x64 + B 256x64), each split in 2 k-slices
// of 32: unit = [256 rows][4 slots][16B] (16 KB, staged by 2 gload_lds/thr).
// Slot swizzle: global chunk c of row r lives at slot c ^ ((r>>1)&3) ->
// ds_read_b128 is 2-lane/bank optimal; stage pre-swizzles the GLOBAL addr.
// Pipeline: phases stage 1 unit each, 3 units (6 loads) stay in flight;
// s_waitcnt vmcnt(6) ONLY at end of phases 3 and 7 (never 0 in the loop).
// phase arg: 1 = K section (fused kv reduction), 0 = Q section (out write).
// ---------------------------------------------------------------------------
#define BUFSZ 8192  // u16 elems per 16 KB unit
#define UOFF(buf, mat, ks) (((((buf)*2 + (mat))*2 + (ks))) * BUFSZ)

__global__ __launch_bounds__(512, 2) void gemm_qkv(
    const u16* __restrict__ qb, const u16* __restrict__ WbT,
    const float* __restrict__ bcat, const void* __restrict__ maskp,
    const int* __restrict__ mmode,
    const float* __restrict__ sV, float* __restrict__ kv,
    float* __restrict__ out, int phase) {
  __shared__ __align__(16) u16 lds[65536];  // 128 KB
  const int tid = threadIdx.x;
  const int lane = tid & 63;
  const int w = tid >> 6;          // 0..7
  const int wm = w & 1, wn = w >> 1;
  const int l15 = lane & 15, l16 = lane >> 4;

  // T1: bijective XCD swizzle (512 blocks, 512 % 8 == 0)
  const int bid = blockIdx.x;
  const int swz = (bid & 7) * 64 + (bid >> 3);
  const int mt = swz >> 2;         // 0..127
  const int nt = swz & 3;          // 0..3
  const int row0 = mt * 256;
  const int col0 = (phase ? 1024 : 0) + nt * 256;

  f32x4 acc[8][4] = {};

#define STAGE(buf, mat, ks, kt) do {                                        \
    const u16* gb_ = (mat) ? (WbT + (size_t)col0 * DD)                      \
                           : (qb + (size_t)row0 * DD);                      \
    const int kt_ = (kt) & 15;                                              \
    _Pragma("unroll")                                                       \
    for (int j_ = 0; j_ < 2; ++j_) {                                        \
      int li_ = tid + j_ * 512;                                             \
      int row_ = li_ >> 2, slot_ = li_ & 3;                                 \
      int c_ = slot_ ^ ((row_ >> 1) & 3);                                   \
      async16(gb_ + (size_t)row_ * DD + kt_ * 64 + (ks) * 32 + c_ * 8,      \
              lds + UOFF(buf, mat, ks) + li_ * 8);                          \
    }                                                                       \
  } while (0)

#define LDA(buf, ks, a) do {                                                \
    _Pragma("unroll")                                                       \
    for (int mi_ = 0; mi_ < 8; ++mi_) {                                     \
      int r_ = wm * 128 + mi_ * 16 + l15;                                   \
      a[mi_] = *(const s16x8*)(lds + UOFF(buf, 0, ks) + r_ * 32 +           \
                               ((l16 ^ ((r_ >> 1) & 3)) * 8));              \
    }                                                                       \
  } while (0)

#define LDB2(buf, ks, nb, b) do {                                           \
    _Pragma("unroll")                                                       \
    for (int q_ = 0; q_ < 2; ++q_) {                                        \
      int r_ = wn * 64 + ((nb)*2 + q_) * 16 + l15;                          \
      b[q_] = *(const s16x8*)(lds + UOFF(buf, 1, ks) + r_ * 32 +            \
                              ((l16 ^ ((r_ >> 1) & 3)) * 8));               \
    }                                                                       \
  } while (0)

#define MM(a, b, nb) do {                                                   \
    __builtin_amdgcn_s_setprio(1);                                          \
    _Pragma("unroll")                                                       \
    for (int mi_ = 0; mi_ < 8; ++mi_) {                                     \
      acc[mi_][(nb)*2] = __builtin_amdgcn_mfma_f32_16x16x32_bf16(           \
          a[mi_], b[0], acc[mi_][(nb)*2], 0, 0, 0);                         \
      acc[mi_][(nb)*2 + 1] = __builtin_amdgcn_mfma_f32_16x16x32_bf16(       \
          a[mi_], b[1], acc[mi_][(nb)*2 + 1], 0, 0, 0);                     \
    }                                                                       \
    __builtin_amdgcn_s_setprio(0);                                          \
  } while (0)

#define BAR() __builtin_amdgcn_s_barrier()
#define VMW6() asm volatile("s_waitcnt vmcnt(6)" ::: "memory")

  // prologue: tile0 (4 units -> buf0), tile1 first 3 units (-> buf1)
  STAGE(0, 0, 0, 0); STAGE(0, 1, 0, 0); STAGE(0, 0, 1, 0); STAGE(0, 1, 1, 0);
  STAGE(1, 0, 0, 1); STAGE(1, 1, 0, 1); STAGE(1, 0, 1, 1);
  VMW6();   // retire tile0's 8 loads; 6 remain in flight
  BAR();

  for (int t = 0; t < 16; t += 2) {
    s16x8 a[8], b[2];
    // p0: buf0 A[k0] + B[k0,nh0]; stage B-buf1-k1 (tile t+1)
    LDA(0, 0, a); LDB2(0, 0, 0, b);
    STAGE(1, 1, 1, t + 1);
    BAR(); MM(a, b, 0); BAR();
    // p1: B[k0,nh1]; stage A-buf0-k0 (tile t+2)
    LDB2(0, 0, 1, b);
    STAGE(0, 0, 0, t + 2);
    BAR(); MM(a, b, 1); BAR();
    // p2: A[k1] + B[k1,nh0]; stage B-buf0-k0 (tile t+2)
    LDA(0, 1, a); LDB2(0, 1, 0, b);
    STAGE(0, 1, 0, t + 2);
    BAR(); MM(a, b, 0); BAR();
    // p3: B[k1,nh1]; stage A-buf0-k1 (tile t+2); vmcnt(6) -> tile t+1 ready
    LDB2(0, 1, 1, b);
    STAGE(0, 0, 1, t + 2);
    BAR(); MM(a, b, 1); VMW6(); BAR();
    // p4: buf1 A[k0] + B[k0,nh0]; stage B-buf0-k1 (tile t+2)
    LDA(1, 0, a); LDB2(1, 0, 0, b);
    STAGE(0, 1, 1, t + 2);
    BAR(); MM(a, b, 0); BAR();
    // p5: B[k0,nh1]; stage A-buf1-k0 (tile t+3)
    LDB2(1, 0, 1, b);
    STAGE(1, 0, 0, t + 3);
    BAR(); MM(a, b, 1); BAR();
    // p6: A[k1] + B[k1,nh0]; stage B-buf1-k0 (tile t+3)
    LDA(1, 1, a); LDB2(1, 1, 0, b);
    STAGE(1, 1, 0, t + 3);
    BAR(); MM(a, b, 0); BAR();
    // p7: B[k1,nh1]; stage A-buf1-k1 (tile t+3); vmcnt(6) -> tile t+2 ready
    LDB2(1, 1, 1, b);
    STAGE(1, 0, 1, t + 3);
    BAR(); MM(a, b, 1); VMW6(); BAR();
  }

  // ---- epilogue ----
  const int mode = *mmode;
  const int lanec = lane & 15, laneq = lane >> 4;
  const int wcol0 = col0 + wn * 64;  // wave spans exactly one 64-col group
  const int b_ = row0 >> 13;         // batch (rows never cross batch)

  if (phase == 1) {
    // K section with fused kv_sum reduction
    const int n = (wcol0 - 1024) >> 6;  // head, uniform per wave
    float pc[4] = {0.f, 0.f, 0.f, 0.f};
#pragma unroll
    for (int mi = 0; mi < 8; ++mi) {
#pragma unroll
      for (int r = 0; r < 4; ++r) {
        const int row = row0 + wm * 128 + mi * 16 + laneq * 4 + r;
        const bool msk = get_mask(maskp, row, mode);
        if (!msk) {
          const float sv = sV[(size_t)row * NH + n];
#pragma unroll
          for (int ni = 0; ni < 4; ++ni) {
            const int col = wcol0 + ni * 16 + lanec;
            float v = acc[mi][ni][r] + bcat[col];
            float phi = v > 0.f ? v + 1.f : __expf(v);
            pc[ni] += phi * sv;
          }
        }
      }
    }
#pragma unroll
    for (int ni = 0; ni < 4; ++ni) {
      pc[ni] += __shfl_xor(pc[ni], 16);
      pc[ni] += __shfl_xor(pc[ni], 32);
    }
    if (laneq == 0) {
#pragma unroll
      for (int ni = 0; ni < 4; ++ni) {
        const int colk = wcol0 - 1024 + ni * 16 + lanec;  // 0..1023
        atomicAdd(&kv[b_ * DD + colk], pc[ni]);
      }
    }
  } else {
    // Q section -> out = phi * kv_sum (finalize fused)
    float kvv[4];
#pragma unroll
    for (int ni = 0; ni < 4; ++ni)
      kvv[ni] = kv[b_ * DD + wcol0 + ni * 16 + lanec];
#pragma unroll
    for (int mi = 0; mi < 8; ++mi) {
#pragma unroll
      for (int r = 0; r < 4; ++r) {
        const int row = row0 + wm * 128 + mi * 16 + laneq * 4 + r;
#pragma unroll
        for (int ni = 0; ni < 4; ++ni) {
          const int col = wcol0 + ni * 16 + lanec;
          float v = acc[mi][ni][r] + bcat[col];
          float phi = v > 0.f ? v + 1.f : __expf(v);
          out[(size_t)row * DD + col] = phi * kvv[ni];
        }
      }
    }
  }
}

extern "C" void kernel_launch(void* const* d_in, const int* in_sizes, int n_in,
                              void* d_out, int out_size, void* d_ws, size_t ws_size,
                              hipStream_t stream) {
  const float* query = (const float*)d_in[0];
  const void* maskp = d_in[1];
  const float* Wq = (const float*)d_in[2];
  const float* bq = (const float*)d_in[3];
  const float* Wk = (const float*)d_in[4];
  const float* bk = (const float*)d_in[5];
  const float* Wv = (const float*)d_in[6];
  const float* bv = (const float*)d_in[7];
  float* out = (float*)d_out;

  char* ws = (char*)d_ws;
  u16* qb = (u16*)ws;            ws += (size_t)MROWS * DD * 2;      // 64 MB
  u16* WbT = (u16*)ws;           ws += (size_t)NWBT * DD * 2;       // ~4.2 MB
  float* sV = (float*)ws;        ws += (size_t)MROWS * NH * 4;      // 2 MB
  float* bcat = (float*)ws;      ws += (size_t)NWBT * 4;
  float* kv = (float*)ws;        ws += (size_t)BB * DD * 4;         // 16 KB
  int* mflag = (int*)ws;         ws += 256;

  // zero kv_sum + mask-mode flag
  hipMemsetAsync(kv, 0, (size_t)BB * DD * 4 + 256, stream);

  detect_mask<<<32, 256, 0, stream>>>((const u32*)maskp, mflag);
  build_wbt<<<dim3(2048 / 32, DD / 32), dim3(32, 8), 0, stream>>>(Wq, Wk, WbT);
  build_wvs<<<64, 256, 0, stream>>>(Wv, WbT);
  build_bcat<<<(NWBT + 255) / 256, 256, 0, stream>>>(bq, bk, bv, bcat);
  // fused cvt + sV
  prep_q<<<MROWS / 128, 256, 0, stream>>>(query, WbT, bcat, maskp, mflag, qb, sV);
  // K phase first: kv_sum (fused reduction, no phiK materialization)
  gemm_qkv<<<512, 512, 0, stream>>>(qb, WbT, bcat, maskp, mflag, sV, kv, out, 1);
  // Q phase: out = phiQ * kv_sum (finalize fused, no phiQ materialization)
  gemm_qkv<<<512, 512, 0, stream>>>(qb, WbT, bcat, maskp, mflag, sV, kv, out, 0);
}

// Round 3
// 418.231 us; speedup vs baseline: 1.1609x; 1.0267x over previous
//
#include <hip/hip_runtime.h>

typedef unsigned short u16;
typedef unsigned int u32;
typedef __attribute__((ext_vector_type(8))) short s16x8;
typedef __attribute__((ext_vector_type(4))) float f32x4;

#define GAS __attribute__((address_space(1)))
#define LAS __attribute__((address_space(3)))

// ---- constants ----
#define BB 4
#define LL 8192
#define DD 1024
#define NH 16
#define HD 64
#define MROWS (BB * LL)          // 32768
#define NWBT 2064                // 1024 Q + 1024 K + 16 WvS rows

__device__ __forceinline__ u16 f2bf(float f) {
  u32 u = __builtin_bit_cast(u32, f);
  u32 r = (u + 0x7FFFu + ((u >> 16) & 1u)) >> 16;
  return (u16)r;
}
__device__ __forceinline__ float bf2f(u32 lo) {
  return __builtin_bit_cast(float, lo << 16);
}

__device__ __forceinline__ void async16(const void* g, void* l) {
  __builtin_amdgcn_global_load_lds((const GAS u32*)g, (LAS u32*)l, 16, 0, 0);
}

// mask encoding modes: 0 = int32, 1 = float32, 2 = uint8
__device__ __forceinline__ bool get_mask(const void* mp, int row, int mode) {
  if (mode == 2) return ((const unsigned char*)mp)[row] != 0;
  if (mode == 1) return ((const float*)mp)[row] != 0.f;
  return ((const int*)mp)[row] != 0;
}

// Build WbT[n][k] = W{q,k}[k][n mod 1024] as bf16 (transposed, 32x32 LDS tiles)
__global__ void build_wbt(const float* __restrict__ Wq, const float* __restrict__ Wk,
                          u16* __restrict__ WbT) {
  __shared__ float t[32][33];
  const int n0 = blockIdx.x * 32;  // 0..2047
  const int k0 = blockIdx.y * 32;  // 0..1023
  const float* W = (n0 >> 10) == 0 ? Wq : Wk;
  const int nloc = n0 & 1023;
  const int tx = threadIdx.x, ty = threadIdx.y;  // 32 x 8
#pragma unroll
  for (int j = 0; j < 32; j += 8)
    t[ty + j][tx] = W[(size_t)(k0 + ty + j) * DD + nloc + tx];
  __syncthreads();
#pragma unroll
  for (int j = 0; j < 32; j += 8)
    WbT[(size_t)(n0 + ty + j) * DD + k0 + tx] = f2bf(t[tx][ty + j]);
}

// Merged small-prep kernel (105 blocks x 256):
//  blocks 0..63   : WbT rows 2048..2063  WvS[h][k] = sum_j Wv[k][h*64+j]
//  blocks 64..72  : bcat  [0..1023]=bq, [1024..2047]=bk, [2048+h]=sum bv
//  blocks 73..104 : mask dtype detection (8192 words)
__global__ void build_aux(const float* __restrict__ Wv, const float* __restrict__ bq,
                          const float* __restrict__ bk, const float* __restrict__ bv,
                          const u32* __restrict__ m,
                          u16* __restrict__ WbT, float* __restrict__ bcat,
                          int* __restrict__ flag) {
  const int blk = blockIdx.x;
  const int tid = threadIdx.x;
  if (blk < 64) {
    int i = blk * 256 + tid;  // 0..16383: k = i>>4, h = i&15
    int k = i >> 4, h = i & 15;
    float s = 0.f;
    const float* p = Wv + (size_t)k * DD + h * HD;
#pragma unroll 8
    for (int j = 0; j < 64; ++j) s += p[j];
    WbT[(size_t)(2048 + h) * DD + k] = f2bf(s);
  } else if (blk < 73) {
    int i = (blk - 64) * 256 + tid;
    if (i < 1024) bcat[i] = bq[i];
    else if (i < 2048) bcat[i] = bk[i - 1024];
    else if (i < 2064) {
      float s = 0.f;
      const float* p = bv + (i - 2048) * HD;
#pragma unroll 8
      for (int j = 0; j < 64; ++j) s += p[j];
      bcat[i] = s;
    }
  } else {
    int i = (blk - 73) * 256 + tid;  // 0..8191
    u32 v = m[i];
    int f = 0;
    if (v == 0x3F800000u) f = 1;       // looks like float 1.0
    else if (v > 1u) f = 2;            // packed bytes -> uint8
    if (f) atomicMax(flag, f);
  }
}

// Fused query fp32->bf16 conversion + sV GEMM, v2 (occupancy-fixed).
// 64 rows/block -> 512 blocks (2/CU resident), 4 waves, LDS 40 KB.
// Wave w owns row-tile w (16 rows x 16 heads), does both K-halves of each
// 64-wide step -> no cross-wave reduction. Same swizzle math as the GEMM.
__global__ __launch_bounds__(256) void prep_q(
    const float* __restrict__ query, const u16* __restrict__ WbT,
    const float* __restrict__ bcat, const void* __restrict__ maskp,
    const int* __restrict__ mmode,
    u16* __restrict__ qb, float* __restrict__ sV) {
  __shared__ u16 ldsW[16 * 1024];  // 32 KB, chunk-swizzled WvS panel
  __shared__ u16 ldsA[64 * 64];    // 8 KB, per-step A tile
  const int tid = threadIdx.x;
  const int lane = tid & 63;
  const int w = tid >> 6;          // 0..3
  const int l15 = lane & 15, l16 = lane >> 4;
  const int row0 = blockIdx.x * 64;

  // stage WvS panel (coalesced: consecutive tid -> consecutive chunks)
#pragma unroll
  for (int j = 0; j < 8; ++j) {
    int idx = tid + j * 256;       // 0..2047
    int h = idx >> 7, c = idx & 127;
    s16x8 v = *(const s16x8*)(WbT + (size_t)(2048 + h) * DD + c * 8);
    *(s16x8*)(ldsW + h * 1024 + (c ^ (h & 7)) * 8) = v;
  }

  f32x4 acc = {};
  for (int k0 = 0; k0 < DD; k0 += 64) {
    __syncthreads();
#pragma unroll
    for (int j = 0; j < 2; ++j) {
      int li = tid + j * 256;      // 0..511
      int row = li >> 3, slot = li & 7;
      int seg = slot ^ (row & 7);  // global k-segment fetched (swizzle)
      const float* gp = query + (size_t)(row0 + row) * DD + k0 + seg * 8;
      float4 v0 = *(const float4*)gp;
      float4 v1 = *(const float4*)(gp + 4);
      s16x8 o;
      o[0] = (short)f2bf(v0.x); o[1] = (short)f2bf(v0.y);
      o[2] = (short)f2bf(v0.z); o[3] = (short)f2bf(v0.w);
      o[4] = (short)f2bf(v1.x); o[5] = (short)f2bf(v1.y);
      o[6] = (short)f2bf(v1.z); o[7] = (short)f2bf(v1.w);
      *(s16x8*)(qb + (size_t)(row0 + row) * DD + k0 + seg * 8) = o;
      *(s16x8*)(ldsA + row * 64 + slot * 8) = o;
    }
    __syncthreads();
#pragma unroll
    for (int kk = 0; kk < 2; ++kk) {
      const int segk = kk * 4 + l16;
      const int r = w * 16 + l15;
      s16x8 af = *(const s16x8*)(ldsA + r * 64 + ((segk ^ (r & 7))) * 8);
      const int cc = (k0 >> 3) + segk;  // global 8-elem chunk index
      s16x8 bfr = *(const s16x8*)(ldsW + l15 * 1024 + ((cc ^ (l15 & 7))) * 8);
      acc = __builtin_amdgcn_mfma_f32_16x16x32_bf16(af, bfr, acc, 0, 0, 0);
    }
  }

  const int mode = *mmode;
#pragma unroll
  for (int r = 0; r < 4; ++r) {
    const int row = row0 + w * 16 + l16 * 4 + r;
    const bool msk = get_mask(maskp, row, mode);
    float v = acc[r] + bcat[2048 + l15];
    sV[(size_t)row * NH + l15] = msk ? 0.f : v;
  }
}

// ---------------------------------------------------------------------------
// 256x256-tile, 8-phase, counted-vmcnt projection GEMM (T1+T2+T3+T4+T5).
// (unchanged from round 2 — verified)
// ---------------------------------------------------------------------------
#define BUFSZ 8192  // u16 elems per 16 KB unit
#define UOFF(buf, mat, ks) (((((buf)*2 + (mat))*2 + (ks))) * BUFSZ)

__global__ __launch_bounds__(512, 2) void gemm_qkv(
    const u16* __restrict__ qb, const u16* __restrict__ WbT,
    const float* __restrict__ bcat, const void* __restrict__ maskp,
    const int* __restrict__ mmode,
    const float* __restrict__ sV, float* __restrict__ kv,
    float* __restrict__ out, int phase) {
  __shared__ __align__(16) u16 lds[65536];  // 128 KB
  const int tid = threadIdx.x;
  const int lane = tid & 63;
  const int w = tid >> 6;          // 0..7
  const int wm = w & 1, wn = w >> 1;
  const int l15 = lane & 15, l16 = lane >> 4;

  // T1: bijective XCD swizzle (512 blocks, 512 % 8 == 0)
  const int bid = blockIdx.x;
  const int swz = (bid & 7) * 64 + (bid >> 3);
  const int mt = swz >> 2;         // 0..127
  const int nt = swz & 3;          // 0..3
  const int row0 = mt * 256;
  const int col0 = (phase ? 1024 : 0) + nt * 256;

  f32x4 acc[8][4] = {};

#define STAGE(buf, mat, ks, kt) do {                                        \
    const u16* gb_ = (mat) ? (WbT + (size_t)col0 * DD)                      \
                           : (qb + (size_t)row0 * DD);                      \
    const int kt_ = (kt) & 15;                                              \
    _Pragma("unroll")                                                       \
    for (int j_ = 0; j_ < 2; ++j_) {                                        \
      int li_ = tid + j_ * 512;                                             \
      int row_ = li_ >> 2, slot_ = li_ & 3;                                 \
      int c_ = slot_ ^ ((row_ >> 1) & 3);                                   \
      async16(gb_ + (size_t)row_ * DD + kt_ * 64 + (ks) * 32 + c_ * 8,      \
              lds + UOFF(buf, mat, ks) + li_ * 8);                          \
    }                                                                       \
  } while (0)

#define LDA(buf, ks, a) do {                                                \
    _Pragma("unroll")                                                       \
    for (int mi_ = 0; mi_ < 8; ++mi_) {                                     \
      int r_ = wm * 128 + mi_ * 16 + l15;                                   \
      a[mi_] = *(const s16x8*)(lds + UOFF(buf, 0, ks) + r_ * 32 +           \
                               ((l16 ^ ((r_ >> 1) & 3)) * 8));              \
    }                                                                       \
  } while (0)

#define LDB2(buf, ks, nb, b) do {                                           \
    _Pragma("unroll")                                                       \
    for (int q_ = 0; q_ < 2; ++q_) {                                        \
      int r_ = wn * 64 + ((nb)*2 + q_) * 16 + l15;                          \
      b[q_] = *(const s16x8*)(lds + UOFF(buf, 1, ks) + r_ * 32 +            \
                              ((l16 ^ ((r_ >> 1) & 3)) * 8));               \
    }                                                                       \
  } while (0)

#define MM(a, b, nb) do {                                                   \
    __builtin_amdgcn_s_setprio(1);                                          \
    _Pragma("unroll")                                                       \
    for (int mi_ = 0; mi_ < 8; ++mi_) {                                     \
      acc[mi_][(nb)*2] = __builtin_amdgcn_mfma_f32_16x16x32_bf16(           \
          a[mi_], b[0], acc[mi_][(nb)*2], 0, 0, 0);                         \
      acc[mi_][(nb)*2 + 1] = __builtin_amdgcn_mfma_f32_16x16x32_bf16(       \
          a[mi_], b[1], acc[mi_][(nb)*2 + 1], 0, 0, 0);                     \
    }                                                                       \
    __builtin_amdgcn_s_setprio(0);                                          \
  } while (0)

#define BAR() __builtin_amdgcn_s_barrier()
#define VMW6() asm volatile("s_waitcnt vmcnt(6)" ::: "memory")

  // prologue: tile0 (4 units -> buf0), tile1 first 3 units (-> buf1)
  STAGE(0, 0, 0, 0); STAGE(0, 1, 0, 0); STAGE(0, 0, 1, 0); STAGE(0, 1, 1, 0);
  STAGE(1, 0, 0, 1); STAGE(1, 1, 0, 1); STAGE(1, 0, 1, 1);
  VMW6();   // retire tile0's 8 loads; 6 remain in flight
  BAR();

  for (int t = 0; t < 16; t += 2) {
    s16x8 a[8], b[2];
    // p0: buf0 A[k0] + B[k0,nh0]; stage B-buf1-k1 (tile t+1)
    LDA(0, 0, a); LDB2(0, 0, 0, b);
    STAGE(1, 1, 1, t + 1);
    BAR(); MM(a, b, 0); BAR();
    // p1: B[k0,nh1]; stage A-buf0-k0 (tile t+2)
    LDB2(0, 0, 1, b);
    STAGE(0, 0, 0, t + 2);
    BAR(); MM(a, b, 1); BAR();
    // p2: A[k1] + B[k1,nh0]; stage B-buf0-k0 (tile t+2)
    LDA(0, 1, a); LDB2(0, 1, 0, b);
    STAGE(0, 1, 0, t + 2);
    BAR(); MM(a, b, 0); BAR();
    // p3: B[k1,nh1]; stage A-buf0-k1 (tile t+2); vmcnt(6) -> tile t+1 ready
    LDB2(0, 1, 1, b);
    STAGE(0, 0, 1, t + 2);
    BAR(); MM(a, b, 1); VMW6(); BAR();
    // p4: buf1 A[k0] + B[k0,nh0]; stage B-buf0-k1 (tile t+2)
    LDA(1, 0, a); LDB2(1, 0, 0, b);
    STAGE(0, 1, 1, t + 2);
    BAR(); MM(a, b, 0); BAR();
    // p5: B[k0,nh1]; stage A-buf1-k0 (tile t+3)
    LDB2(1, 0, 1, b);
    STAGE(1, 0, 0, t + 3);
    BAR(); MM(a, b, 1); BAR();
    // p6: A[k1] + B[k1,nh0]; stage B-buf1-k0 (tile t+3)
    LDA(1, 1, a); LDB2(1, 1, 0, b);
    STAGE(1, 1, 0, t + 3);
    BAR(); MM(a, b, 0); BAR();
    // p7: B[k1,nh1]; stage A-buf1-k1 (tile t+3); vmcnt(6) -> tile t+2 ready
    LDB2(1, 1, 1, b);
    STAGE(1, 0, 1, t + 3);
    BAR(); MM(a, b, 1); VMW6(); BAR();
  }

  // ---- epilogue ----
  const int mode = *mmode;
  const int lanec = lane & 15, laneq = lane >> 4;
  const int wcol0 = col0 + wn * 64;  // wave spans exactly one 64-col group
  const int b_ = row0 >> 13;         // batch (rows never cross batch)

  if (phase == 1) {
    // K section with fused kv_sum reduction
    const int n = (wcol0 - 1024) >> 6;  // head, uniform per wave
    float pc[4] = {0.f, 0.f, 0.f, 0.f};
#pragma unroll
    for (int mi = 0; mi < 8; ++mi) {
#pragma unroll
      for (int r = 0; r < 4; ++r) {
        const int row = row0 + wm * 128 + mi * 16 + laneq * 4 + r;
        const bool msk = get_mask(maskp, row, mode);
        if (!msk) {
          const float sv = sV[(size_t)row * NH + n];
#pragma unroll
          for (int ni = 0; ni < 4; ++ni) {
            const int col = wcol0 + ni * 16 + lanec;
            float v = acc[mi][ni][r] + bcat[col];
            float phi = v > 0.f ? v + 1.f : __expf(v);
            pc[ni] += phi * sv;
          }
        }
      }
    }
#pragma unroll
    for (int ni = 0; ni < 4; ++ni) {
      pc[ni] += __shfl_xor(pc[ni], 16);
      pc[ni] += __shfl_xor(pc[ni], 32);
    }
    if (laneq == 0) {
#pragma unroll
      for (int ni = 0; ni < 4; ++ni) {
        const int colk = wcol0 - 1024 + ni * 16 + lanec;  // 0..1023
        atomicAdd(&kv[b_ * DD + colk], pc[ni]);
      }
    }
  } else {
    // Q section -> out = phi * kv_sum (finalize fused)
    float kvv[4];
#pragma unroll
    for (int ni = 0; ni < 4; ++ni)
      kvv[ni] = kv[b_ * DD + wcol0 + ni * 16 + lanec];
#pragma unroll
    for (int mi = 0; mi < 8; ++mi) {
#pragma unroll
      for (int r = 0; r < 4; ++r) {
        const int row = row0 + wm * 128 + mi * 16 + laneq * 4 + r;
#pragma unroll
        for (int ni = 0; ni < 4; ++ni) {
          const int col = wcol0 + ni * 16 + lanec;
          float v = acc[mi][ni][r] + bcat[col];
          float phi = v > 0.f ? v + 1.f : __expf(v);
          out[(size_t)row * DD + col] = phi * kvv[ni];
        }
      }
    }
  }
}

extern "C" void kernel_launch(void* const* d_in, const int* in_sizes, int n_in,
                              void* d_out, int out_size, void* d_ws, size_t ws_size,
                              hipStream_t stream) {
  const float* query = (const float*)d_in[0];
  const void* maskp = d_in[1];
  const float* Wq = (const float*)d_in[2];
  const float* bq = (const float*)d_in[3];
  const float* Wk = (const float*)d_in[4];
  const float* bk = (const float*)d_in[5];
  const float* Wv = (const float*)d_in[6];
  const float* bv = (const float*)d_in[7];
  float* out = (float*)d_out;

  char* ws = (char*)d_ws;
  u16* qb = (u16*)ws;            ws += (size_t)MROWS * DD * 2;      // 64 MB
  u16* WbT = (u16*)ws;           ws += (size_t)NWBT * DD * 2;       // ~4.2 MB
  float* sV = (float*)ws;        ws += (size_t)MROWS * NH * 4;      // 2 MB
  float* bcat = (float*)ws;      ws += (size_t)NWBT * 4;
  float* kv = (float*)ws;        ws += (size_t)BB * DD * 4;         // 16 KB
  int* mflag = (int*)ws;         ws += 256;

  // zero kv_sum + mask-mode flag (contiguous in workspace)
  hipMemsetAsync(kv, 0, (size_t)BB * DD * 4 + 256, stream);

  build_wbt<<<dim3(2048 / 32, DD / 32), dim3(32, 8), 0, stream>>>(Wq, Wk, WbT);
  build_aux<<<105, 256, 0, stream>>>(Wv, bq, bk, bv, (const u32*)maskp, WbT, bcat, mflag);
  // fused cvt + sV (occupancy-fixed v2)
  prep_q<<<MROWS / 64, 256, 0, stream>>>(query, WbT, bcat, maskp, mflag, qb, sV);
  // K phase first: kv_sum (fused reduction, no phiK materialization)
  gemm_qkv<<<512, 512, 0, stream>>>(qb, WbT, bcat, maskp, mflag, sV, kv, out, 1);
  // Q phase: out = phiQ * kv_sum (finalize fused, no phiQ materialization)
  gemm_qkv<<<512, 512, 0, stream>>>(qb, WbT, bcat, maskp, mflag, sV, kv, out, 0);
}

// Round 4
// 412.126 us; speedup vs baseline: 1.1781x; 1.0148x over previous
//
#include <hip/hip_runtime.h>

typedef unsigned short u16;
typedef unsigned int u32;
typedef __attribute__((ext_vector_type(8))) short s16x8;
typedef __attribute__((ext_vector_type(4))) float f32x4;

#define GAS __attribute__((address_space(1)))
#define LAS __attribute__((address_space(3)))

// ---- constants ----
#define BB 4
#define LL 8192
#define DD 1024
#define NH 16
#define HD 64
#define MROWS (BB * LL)          // 32768
#define NWBT 2064                // 1024 Q + 1024 K + 16 WvS rows

__device__ __forceinline__ u16 f2bf(float f) {
  u32 u = __builtin_bit_cast(u32, f);
  u32 r = (u + 0x7FFFu + ((u >> 16) & 1u)) >> 16;
  return (u16)r;
}
__device__ __forceinline__ float bf2f(u32 lo) {
  return __builtin_bit_cast(float, lo << 16);
}

__device__ __forceinline__ void async16(const void* g, void* l) {
  __builtin_amdgcn_global_load_lds((const GAS u32*)g, (LAS u32*)l, 16, 0, 0);
}

// mask encoding modes: 0 = int32, 1 = float32, 2 = uint8
__device__ __forceinline__ bool get_mask(const void* mp, int row, int mode) {
  if (mode == 2) return ((const unsigned char*)mp)[row] != 0;
  if (mode == 1) return ((const float*)mp)[row] != 0.f;
  return ((const int*)mp)[row] != 0;
}

// Build WbT[n][k] = W{q,k}[k][n mod 1024] as bf16 (transposed, 32x32 LDS tiles)
__global__ void build_wbt(const float* __restrict__ Wq, const float* __restrict__ Wk,
                          u16* __restrict__ WbT) {
  __shared__ float t[32][33];
  const int n0 = blockIdx.x * 32;  // 0..2047
  const int k0 = blockIdx.y * 32;  // 0..1023
  const float* W = (n0 >> 10) == 0 ? Wq : Wk;
  const int nloc = n0 & 1023;
  const int tx = threadIdx.x, ty = threadIdx.y;  // 32 x 8
#pragma unroll
  for (int j = 0; j < 32; j += 8)
    t[ty + j][tx] = W[(size_t)(k0 + ty + j) * DD + nloc + tx];
  __syncthreads();
#pragma unroll
  for (int j = 0; j < 32; j += 8)
    WbT[(size_t)(n0 + ty + j) * DD + k0 + tx] = f2bf(t[tx][ty + j]);
}

// Merged small-prep kernel (105 blocks x 256):
//  blocks 0..63   : WbT rows 2048..2063  WvS[h][k] = sum_j Wv[k][h*64+j]
//  blocks 64..72  : bcat  [0..1023]=bq, [1024..2047]=bk, [2048+h]=sum bv
//  blocks 73..104 : mask dtype detection (8192 words)
__global__ void build_aux(const float* __restrict__ Wv, const float* __restrict__ bq,
                          const float* __restrict__ bk, const float* __restrict__ bv,
                          const u32* __restrict__ m,
                          u16* __restrict__ WbT, float* __restrict__ bcat,
                          int* __restrict__ flag) {
  const int blk = blockIdx.x;
  const int tid = threadIdx.x;
  if (blk < 64) {
    int i = blk * 256 + tid;  // 0..16383: k = i>>4, h = i&15
    int k = i >> 4, h = i & 15;
    float s = 0.f;
    const float* p = Wv + (size_t)k * DD + h * HD;
#pragma unroll 8
    for (int j = 0; j < 64; ++j) s += p[j];
    WbT[(size_t)(2048 + h) * DD + k] = f2bf(s);
  } else if (blk < 73) {
    int i = (blk - 64) * 256 + tid;
    if (i < 1024) bcat[i] = bq[i];
    else if (i < 2048) bcat[i] = bk[i - 1024];
    else if (i < 2064) {
      float s = 0.f;
      const float* p = bv + (i - 2048) * HD;
#pragma unroll 8
      for (int j = 0; j < 64; ++j) s += p[j];
      bcat[i] = s;
    }
  } else {
    int i = (blk - 73) * 256 + tid;  // 0..8191
    u32 v = m[i];
    int f = 0;
    if (v == 0x3F800000u) f = 1;       // looks like float 1.0
    else if (v > 1u) f = 2;            // packed bytes -> uint8
    if (f) atomicMax(flag, f);
  }
}

// Fused query fp32->bf16 conversion + sV GEMM, v3 (barrier-free).
// MFMA fragments are loaded DIRECTLY from global memory (A-frag layout:
// row = lane&15, k = (lane>>4)*8 + j), so there is no LDS staging and no
// per-step barrier. Each wave owns a 16-row tile and one K-half (K-split x2);
// partials combine through 2 KB LDS with a single __syncthreads().
// Block = 4 waves = 2 row-tiles x 2 K-halves; grid = 1024 blocks (16 w/CU).
__global__ __launch_bounds__(256) void prep_q(
    const float* __restrict__ query, const u16* __restrict__ WbT,
    const float* __restrict__ bcat, const void* __restrict__ maskp,
    const int* __restrict__ mmode,
    u16* __restrict__ qb, float* __restrict__ sV) {
  __shared__ float sVp[2][16][16];
  const int tid = threadIdx.x;
  const int lane = tid & 63;
  const int w = tid >> 6;          // 0..3
  const int wl = w >> 1;           // local row-tile 0/1
  const int ks = w & 1;            // K-half 0/1
  const int l15 = lane & 15, l16 = lane >> 4;
  const int row0 = blockIdx.x * 32 + wl * 16;
  const int arow = row0 + l15;     // this lane's A-frag row

  const float* qrow = query + (size_t)arow * DD + ks * 512 + l16 * 8;
  u16* qbrow = qb + (size_t)arow * DD + ks * 512 + l16 * 8;
  const u16* wrow = WbT + (size_t)(2048 + l15) * DD + ks * 512 + l16 * 8;

  f32x4 acc = {};
#pragma unroll
  for (int mac = 0; mac < 2; ++mac) {      // 2 macro-steps x 8 k-steps x 32k
    float4 qv[16];
    s16x8 wv[8];
#pragma unroll
    for (int s = 0; s < 8; ++s) {
      const int off = mac * 256 + s * 32;  // element offset within K-half
      qv[s * 2] = *(const float4*)(qrow + off);
      qv[s * 2 + 1] = *(const float4*)(qrow + off + 4);
      wv[s] = *(const s16x8*)(wrow + off);
    }
#pragma unroll
    for (int s = 0; s < 8; ++s) {
      s16x8 o;
      o[0] = (short)f2bf(qv[s * 2].x);     o[1] = (short)f2bf(qv[s * 2].y);
      o[2] = (short)f2bf(qv[s * 2].z);     o[3] = (short)f2bf(qv[s * 2].w);
      o[4] = (short)f2bf(qv[s * 2 + 1].x); o[5] = (short)f2bf(qv[s * 2 + 1].y);
      o[6] = (short)f2bf(qv[s * 2 + 1].z); o[7] = (short)f2bf(qv[s * 2 + 1].w);
      *(s16x8*)(qbrow + mac * 256 + s * 32) = o;
      acc = __builtin_amdgcn_mfma_f32_16x16x32_bf16(o, wv[s], acc, 0, 0, 0);
    }
  }

  // combine K-halves: ks=1 parks partial in LDS; ks=0 adds, masks, stores
  if (ks == 1) {
#pragma unroll
    for (int r = 0; r < 4; ++r) sVp[wl][l16 * 4 + r][l15] = acc[r];
  }
  __syncthreads();
  if (ks == 0) {
    const int mode = *mmode;
#pragma unroll
    for (int r = 0; r < 4; ++r) {
      const int row = row0 + l16 * 4 + r;
      const bool msk = get_mask(maskp, row, mode);
      float v = acc[r] + sVp[wl][l16 * 4 + r][l15] + bcat[2048 + l15];
      sV[(size_t)row * NH + l15] = msk ? 0.f : v;
    }
  }
}

// ---------------------------------------------------------------------------
// 256x256-tile, 8-phase, counted-vmcnt projection GEMM (T1+T2+T3+T4+T5).
// (unchanged from round 2 — verified)
// ---------------------------------------------------------------------------
#define BUFSZ 8192  // u16 elems per 16 KB unit
#define UOFF(buf, mat, ks) (((((buf)*2 + (mat))*2 + (ks))) * BUFSZ)

__global__ __launch_bounds__(512, 2) void gemm_qkv(
    const u16* __restrict__ qb, const u16* __restrict__ WbT,
    const float* __restrict__ bcat, const void* __restrict__ maskp,
    const int* __restrict__ mmode,
    const float* __restrict__ sV, float* __restrict__ kv,
    float* __restrict__ out, int phase) {
  __shared__ __align__(16) u16 lds[65536];  // 128 KB
  const int tid = threadIdx.x;
  const int lane = tid & 63;
  const int w = tid >> 6;          // 0..7
  const int wm = w & 1, wn = w >> 1;
  const int l15 = lane & 15, l16 = lane >> 4;

  // T1: bijective XCD swizzle (512 blocks, 512 % 8 == 0)
  const int bid = blockIdx.x;
  const int swz = (bid & 7) * 64 + (bid >> 3);
  const int mt = swz >> 2;         // 0..127
  const int nt = swz & 3;          // 0..3
  const int row0 = mt * 256;
  const int col0 = (phase ? 1024 : 0) + nt * 256;

  f32x4 acc[8][4] = {};

#define STAGE(buf, mat, ks, kt) do {                                        \
    const u16* gb_ = (mat) ? (WbT + (size_t)col0 * DD)                      \
                           : (qb + (size_t)row0 * DD);                      \
    const int kt_ = (kt) & 15;                                              \
    _Pragma("unroll")                                                       \
    for (int j_ = 0; j_ < 2; ++j_) {                                        \
      int li_ = tid + j_ * 512;                                             \
      int row_ = li_ >> 2, slot_ = li_ & 3;                                 \
      int c_ = slot_ ^ ((row_ >> 1) & 3);                                   \
      async16(gb_ + (size_t)row_ * DD + kt_ * 64 + (ks) * 32 + c_ * 8,      \
              lds + UOFF(buf, mat, ks) + li_ * 8);                          \
    }                                                                       \
  } while (0)

#define LDA(buf, ks, a) do {                                                \
    _Pragma("unroll")                                                       \
    for (int mi_ = 0; mi_ < 8; ++mi_) {                                     \
      int r_ = wm * 128 + mi_ * 16 + l15;                                   \
      a[mi_] = *(const s16x8*)(lds + UOFF(buf, 0, ks) + r_ * 32 +           \
                               ((l16 ^ ((r_ >> 1) & 3)) * 8));              \
    }                                                                       \
  } while (0)

#define LDB2(buf, ks, nb, b) do {                                           \
    _Pragma("unroll")                                                       \
    for (int q_ = 0; q_ < 2; ++q_) {                                        \
      int r_ = wn * 64 + ((nb)*2 + q_) * 16 + l15;                          \
      b[q_] = *(const s16x8*)(lds + UOFF(buf, 1, ks) + r_ * 32 +            \
                              ((l16 ^ ((r_ >> 1) & 3)) * 8));               \
    }                                                                       \
  } while (0)

#define MM(a, b, nb) do {                                                   \
    __builtin_amdgcn_s_setprio(1);                                          \
    _Pragma("unroll")                                                       \
    for (int mi_ = 0; mi_ < 8; ++mi_) {                                     \
      acc[mi_][(nb)*2] = __builtin_amdgcn_mfma_f32_16x16x32_bf16(           \
          a[mi_], b[0], acc[mi_][(nb)*2], 0, 0, 0);                         \
      acc[mi_][(nb)*2 + 1] = __builtin_amdgcn_mfma_f32_16x16x32_bf16(       \
          a[mi_], b[1], acc[mi_][(nb)*2 + 1], 0, 0, 0);                     \
    }                                                                       \
    __builtin_amdgcn_s_setprio(0);                                          \
  } while (0)

#define BAR() __builtin_amdgcn_s_barrier()
#define VMW6() asm volatile("s_waitcnt vmcnt(6)" ::: "memory")

  // prologue: tile0 (4 units -> buf0), tile1 first 3 units (-> buf1)
  STAGE(0, 0, 0, 0); STAGE(0, 1, 0, 0); STAGE(0, 0, 1, 0); STAGE(0, 1, 1, 0);
  STAGE(1, 0, 0, 1); STAGE(1, 1, 0, 1); STAGE(1, 0, 1, 1);
  VMW6();   // retire tile0's 8 loads; 6 remain in flight
  BAR();

  for (int t = 0; t < 16; t += 2) {
    s16x8 a[8], b[2];
    // p0: buf0 A[k0] + B[k0,nh0]; stage B-buf1-k1 (tile t+1)
    LDA(0, 0, a); LDB2(0, 0, 0, b);
    STAGE(1, 1, 1, t + 1);
    BAR(); MM(a, b, 0); BAR();
    // p1: B[k0,nh1]; stage A-buf0-k0 (tile t+2)
    LDB2(0, 0, 1, b);
    STAGE(0, 0, 0, t + 2);
    BAR(); MM(a, b, 1); BAR();
    // p2: A[k1] + B[k1,nh0]; stage B-buf0-k0 (tile t+2)
    LDA(0, 1, a); LDB2(0, 1, 0, b);
    STAGE(0, 1, 0, t + 2);
    BAR(); MM(a, b, 0); BAR();
    // p3: B[k1,nh1]; stage A-buf0-k1 (tile t+2); vmcnt(6) -> tile t+1 ready
    LDB2(0, 1, 1, b);
    STAGE(0, 0, 1, t + 2);
    BAR(); MM(a, b, 1); VMW6(); BAR();
    // p4: buf1 A[k0] + B[k0,nh0]; stage B-buf0-k1 (tile t+2)
    LDA(1, 0, a); LDB2(1, 0, 0, b);
    STAGE(0, 1, 1, t + 2);
    BAR(); MM(a, b, 0); BAR();
    // p5: B[k0,nh1]; stage A-buf1-k0 (tile t+3)
    LDB2(1, 0, 1, b);
    STAGE(1, 0, 0, t + 3);
    BAR(); MM(a, b, 1); BAR();
    // p6: A[k1] + B[k1,nh0]; stage B-buf1-k0 (tile t+3)
    LDA(1, 1, a); LDB2(1, 1, 0, b);
    STAGE(1, 1, 0, t + 3);
    BAR(); MM(a, b, 0); BAR();
    // p7: B[k1,nh1]; stage A-buf1-k1 (tile t+3); vmcnt(6) -> tile t+2 ready
    LDB2(1, 1, 1, b);
    STAGE(1, 0, 1, t + 3);
    BAR(); MM(a, b, 1); VMW6(); BAR();
  }

  // ---- epilogue ----
  const int mode = *mmode;
  const int lanec = lane & 15, laneq = lane >> 4;
  const int wcol0 = col0 + wn * 64;  // wave spans exactly one 64-col group
  const int b_ = row0 >> 13;         // batch (rows never cross batch)

  if (phase == 1) {
    // K section with fused kv_sum reduction
    const int n = (wcol0 - 1024) >> 6;  // head, uniform per wave
    float pc[4] = {0.f, 0.f, 0.f, 0.f};
#pragma unroll
    for (int mi = 0; mi < 8; ++mi) {
#pragma unroll
      for (int r = 0; r < 4; ++r) {
        const int row = row0 + wm * 128 + mi * 16 + laneq * 4 + r;
        const bool msk = get_mask(maskp, row, mode);
        if (!msk) {
          const float sv = sV[(size_t)row * NH + n];
#pragma unroll
          for (int ni = 0; ni < 4; ++ni) {
            const int col = wcol0 + ni * 16 + lanec;
            float v = acc[mi][ni][r] + bcat[col];
            float phi = v > 0.f ? v + 1.f : __expf(v);
            pc[ni] += phi * sv;
          }
        }
      }
    }
#pragma unroll
    for (int ni = 0; ni < 4; ++ni) {
      pc[ni] += __shfl_xor(pc[ni], 16);
      pc[ni] += __shfl_xor(pc[ni], 32);
    }
    if (laneq == 0) {
#pragma unroll
      for (int ni = 0; ni < 4; ++ni) {
        const int colk = wcol0 - 1024 + ni * 16 + lanec;  // 0..1023
        atomicAdd(&kv[b_ * DD + colk], pc[ni]);
      }
    }
  } else {
    // Q section -> out = phi * kv_sum (finalize fused)
    float kvv[4];
#pragma unroll
    for (int ni = 0; ni < 4; ++ni)
      kvv[ni] = kv[b_ * DD + wcol0 + ni * 16 + lanec];
#pragma unroll
    for (int mi = 0; mi < 8; ++mi) {
#pragma unroll
      for (int r = 0; r < 4; ++r) {
        const int row = row0 + wm * 128 + mi * 16 + laneq * 4 + r;
#pragma unroll
        for (int ni = 0; ni < 4; ++ni) {
          const int col = wcol0 + ni * 16 + lanec;
          float v = acc[mi][ni][r] + bcat[col];
          float phi = v > 0.f ? v + 1.f : __expf(v);
          out[(size_t)row * DD + col] = phi * kvv[ni];
        }
      }
    }
  }
}

extern "C" void kernel_launch(void* const* d_in, const int* in_sizes, int n_in,
                              void* d_out, int out_size, void* d_ws, size_t ws_size,
                              hipStream_t stream) {
  const float* query = (const float*)d_in[0];
  const void* maskp = d_in[1];
  const float* Wq = (const float*)d_in[2];
  const float* bq = (const float*)d_in[3];
  const float* Wk = (const float*)d_in[4];
  const float* bk = (const float*)d_in[5];
  const float* Wv = (const float*)d_in[6];
  const float* bv = (const float*)d_in[7];
  float* out = (float*)d_out;

  char* ws = (char*)d_ws;
  u16* qb = (u16*)ws;            ws += (size_t)MROWS * DD * 2;      // 64 MB
  u16* WbT = (u16*)ws;           ws += (size_t)NWBT * DD * 2;       // ~4.2 MB
  float* sV = (float*)ws;        ws += (size_t)MROWS * NH * 4;      // 2 MB
  float* bcat = (float*)ws;      ws += (size_t)NWBT * 4;
  float* kv = (float*)ws;        ws += (size_t)BB * DD * 4;         // 16 KB
  int* mflag = (int*)ws;         ws += 256;

  // zero kv_sum + mask-mode flag (contiguous in workspace)
  hipMemsetAsync(kv, 0, (size_t)BB * DD * 4 + 256, stream);

  build_wbt<<<dim3(2048 / 32, DD / 32), dim3(32, 8), 0, stream>>>(Wq, Wk, WbT);
  build_aux<<<105, 256, 0, stream>>>(Wv, bq, bk, bv, (const u32*)maskp, WbT, bcat, mflag);
  // fused cvt + sV (barrier-free v3)
  prep_q<<<MROWS / 32, 256, 0, stream>>>(query, WbT, bcat, maskp, mflag, qb, sV);
  // K phase first: kv_sum (fused reduction, no phiK materialization)
  gemm_qkv<<<512, 512, 0, stream>>>(qb, WbT, bcat, maskp, mflag, sV, kv, out, 1);
  // Q phase: out = phiQ * kv_sum (finalize fused, no phiQ materialization)
  gemm_qkv<<<512, 512, 0, stream>>>(qb, WbT, bcat, maskp, mflag, sV, kv, out, 0);
}

// Round 6
// 410.492 us; speedup vs baseline: 1.1828x; 1.0040x over previous
//
#include <hip/hip_runtime.h>

typedef unsigned short u16;
typedef unsigned int u32;
typedef __attribute__((ext_vector_type(8))) short s16x8;
typedef __attribute__((ext_vector_type(4))) float f32x4;

#define GAS __attribute__((address_space(1)))
#define LAS __attribute__((address_space(3)))

// ---- constants ----
#define BB 4
#define LL 8192
#define DD 1024
#define NH 16
#define HD 64
#define MROWS (BB * LL)          // 32768
#define NWBT 2064                // 1024 Q + 1024 K + 16 WvS rows

__device__ __forceinline__ u16 f2bf(float f) {
  u32 u = __builtin_bit_cast(u32, f);
  u32 r = (u + 0x7FFFu + ((u >> 16) & 1u)) >> 16;
  return (u16)r;
}
__device__ __forceinline__ float bf2f(u32 lo) {
  return __builtin_bit_cast(float, lo << 16);
}

__device__ __forceinline__ void async16(const void* g, void* l) {
  __builtin_amdgcn_global_load_lds((const GAS u32*)g, (LAS u32*)l, 16, 0, 0);
}

// mask encoding modes: 0 = int32, 1 = float32, 2 = uint8
__device__ __forceinline__ bool get_mask(const void* mp, int row, int mode) {
  if (mode == 2) return ((const unsigned char*)mp)[row] != 0;
  if (mode == 1) return ((const float*)mp)[row] != 0.f;
  return ((const int*)mp)[row] != 0;
}

// Build WbT[n][k] = W{q,k}[k][n mod 1024] as bf16 (transposed, 32x32 LDS tiles)
__global__ void build_wbt(const float* __restrict__ Wq, const float* __restrict__ Wk,
                          u16* __restrict__ WbT) {
  __shared__ float t[32][33];
  const int n0 = blockIdx.x * 32;  // 0..2047
  const int k0 = blockIdx.y * 32;  // 0..1023
  const float* W = (n0 >> 10) == 0 ? Wq : Wk;
  const int nloc = n0 & 1023;
  const int tx = threadIdx.x, ty = threadIdx.y;  // 32 x 8
#pragma unroll
  for (int j = 0; j < 32; j += 8)
    t[ty + j][tx] = W[(size_t)(k0 + ty + j) * DD + nloc + tx];
  __syncthreads();
#pragma unroll
  for (int j = 0; j < 32; j += 8)
    WbT[(size_t)(n0 + ty + j) * DD + k0 + tx] = f2bf(t[tx][ty + j]);
}

// Merged small-prep kernel (105 blocks x 256):
//  blocks 0..63   : WbT rows 2048..2063  WvS[h][k] = sum_j Wv[k][h*64+j]
//  blocks 64..72  : bcat  [0..1023]=bq, [1024..2047]=bk, [2048+h]=sum bv
//  blocks 73..104 : mask dtype detection (8192 words)
__global__ void build_aux(const float* __restrict__ Wv, const float* __restrict__ bq,
                          const float* __restrict__ bk, const float* __restrict__ bv,
                          const u32* __restrict__ m,
                          u16* __restrict__ WbT, float* __restrict__ bcat,
                          int* __restrict__ flag) {
  const int blk = blockIdx.x;
  const int tid = threadIdx.x;
  if (blk < 64) {
    int i = blk * 256 + tid;  // 0..16383: k = i>>4, h = i&15
    int k = i >> 4, h = i & 15;
    float s = 0.f;
    const float* p = Wv + (size_t)k * DD + h * HD;
#pragma unroll 8
    for (int j = 0; j < 64; ++j) s += p[j];
    WbT[(size_t)(2048 + h) * DD + k] = f2bf(s);
  } else if (blk < 73) {
    int i = (blk - 64) * 256 + tid;
    if (i < 1024) bcat[i] = bq[i];
    else if (i < 2048) bcat[i] = bk[i - 1024];
    else if (i < 2064) {
      float s = 0.f;
      const float* p = bv + (i - 2048) * HD;
#pragma unroll 8
      for (int j = 0; j < 64; ++j) s += p[j];
      bcat[i] = s;
    }
  } else {
    int i = (blk - 73) * 256 + tid;  // 0..8191
    u32 v = m[i];
    int f = 0;
    if (v == 0x3F800000u) f = 1;       // looks like float 1.0
    else if (v > 1u) f = 2;            // packed bytes -> uint8
    if (f) atomicMax(flag, f);
  }
}

// Fused query fp32->bf16 conversion + sV GEMM, v3 (barrier-free, verified r4).
// MFMA fragments loaded DIRECTLY from global memory (A-frag layout:
// row = lane&15, k = (lane>>4)*8 + j). Each wave owns a 16-row tile and one
// K-half; partials combine through 2 KB LDS with a single __syncthreads().
__global__ __launch_bounds__(256) void prep_q(
    const float* __restrict__ query, const u16* __restrict__ WbT,
    const float* __restrict__ bcat, const void* __restrict__ maskp,
    const int* __restrict__ mmode,
    u16* __restrict__ qb, float* __restrict__ sV) {
  __shared__ float sVp[2][16][16];
  const int tid = threadIdx.x;
  const int lane = tid & 63;
  const int w = tid >> 6;          // 0..3
  const int wl = w >> 1;           // local row-tile 0/1
  const int ks = w & 1;            // K-half 0/1
  const int l15 = lane & 15, l16 = lane >> 4;
  const int row0 = blockIdx.x * 32 + wl * 16;
  const int arow = row0 + l15;     // this lane's A-frag row

  const float* qrow = query + (size_t)arow * DD + ks * 512 + l16 * 8;
  u16* qbrow = qb + (size_t)arow * DD + ks * 512 + l16 * 8;
  const u16* wrow = WbT + (size_t)(2048 + l15) * DD + ks * 512 + l16 * 8;

  f32x4 acc = {};
#pragma unroll
  for (int mac = 0; mac < 2; ++mac) {      // 2 macro-steps x 8 k-steps x 32k
    float4 qv[16];
    s16x8 wv[8];
#pragma unroll
    for (int s = 0; s < 8; ++s) {
      const int off = mac * 256 + s * 32;  // element offset within K-half
      qv[s * 2] = *(const float4*)(qrow + off);
      qv[s * 2 + 1] = *(const float4*)(qrow + off + 4);
      wv[s] = *(const s16x8*)(wrow + off);
    }
#pragma unroll
    for (int s = 0; s < 8; ++s) {
      s16x8 o;
      o[0] = (short)f2bf(qv[s * 2].x);     o[1] = (short)f2bf(qv[s * 2].y);
      o[2] = (short)f2bf(qv[s * 2].z);     o[3] = (short)f2bf(qv[s * 2].w);
      o[4] = (short)f2bf(qv[s * 2 + 1].x); o[5] = (short)f2bf(qv[s * 2 + 1].y);
      o[6] = (short)f2bf(qv[s * 2 + 1].z); o[7] = (short)f2bf(qv[s * 2 + 1].w);
      *(s16x8*)(qbrow + mac * 256 + s * 32) = o;
      acc = __builtin_amdgcn_mfma_f32_16x16x32_bf16(o, wv[s], acc, 0, 0, 0);
    }
  }

  // combine K-halves: ks=1 parks partial in LDS; ks=0 adds, masks, stores
  if (ks == 1) {
#pragma unroll
    for (int r = 0; r < 4; ++r) sVp[wl][l16 * 4 + r][l15] = acc[r];
  }
  __syncthreads();
  if (ks == 0) {
    const int mode = *mmode;
#pragma unroll
    for (int r = 0; r < 4; ++r) {
      const int row = row0 + l16 * 4 + r;
      const bool msk = get_mask(maskp, row, mode);
      float v = acc[r] + sVp[wl][l16 * 4 + r][l15] + bcat[2048 + l15];
      sV[(size_t)row * NH + l15] = msk ? 0.f : v;
    }
  }
}

// ---------------------------------------------------------------------------
// 128x256-tile projection GEMM, v3: 2 blocks/CU (register-feasible).
// 8 waves (2M x 4N), per-wave output 64x64 -> acc[4][4] = 64 VGPR;
// total regs ~118 <= 128 cap from __launch_bounds__(512,4).
// BK=32; LDS 48 KB = 2 dbuf x (A 128x32 = 8 KB + B 256x32 = 16 KB)
// -> 96 KB per CU at 2 blocks -> 16 waves/CU for cross-block stall hiding.
// Race-free restage (unit rewritten only after the double barrier following
// its last read): B1 in P0, A0 in P1, B0 in P2, A1 in P3.
// Counted vmcnt(1) at P1/P3 (A-unit = 1 load/thread, B-unit = 2);
// vmcnt(0) only in the peeled final iteration. Grid 1024 (%8==0, T1 swizzle).
// phase arg: 1 = K section (fused kv reduction), 0 = Q section (out write).
// ---------------------------------------------------------------------------
#define AOFF(buf) ((buf) * 12288)
#define BOFF(buf) ((buf) * 12288 + 4096)

__global__ __launch_bounds__(512, 4) void gemm_qkv(
    const u16* __restrict__ qb, const u16* __restrict__ WbT,
    const float* __restrict__ bcat, const void* __restrict__ maskp,
    const int* __restrict__ mmode,
    const float* __restrict__ sV, float* __restrict__ kv,
    float* __restrict__ out, int phase) {
  __shared__ __align__(16) u16 lds[24576];  // 48 KB
  const int tid = threadIdx.x;
  const int lane = tid & 63;
  const int w = tid >> 6;          // 0..7
  const int wm = w & 1, wn = w >> 1;
  const int l15 = lane & 15, l16 = lane >> 4;

  // T1: bijective XCD swizzle (1024 blocks, 1024 % 8 == 0)
  const int bid = blockIdx.x;
  const int swz = (bid & 7) * 128 + (bid >> 3);
  const int mt = swz >> 2;         // 0..255
  const int nt = swz & 3;          // 0..3
  const int row0 = mt * 128;
  const int col0 = (phase ? 1024 : 0) + nt * 256;

  f32x4 acc[4][4] = {};

// A-unit: 128 rows x 4 chunks = 512 -> 1 load/thread
#define STAGE_A(buf, kt) do {                                               \
    int row_ = tid >> 2, slot_ = tid & 3;                                   \
    int c_ = slot_ ^ ((row_ >> 1) & 3);                                     \
    async16(qb + (size_t)(row0 + row_) * DD + (kt) * 32 + c_ * 8,           \
            lds + AOFF(buf) + tid * 8);                                     \
  } while (0)

// B-unit: 256 rows x 4 chunks = 1024 -> 2 loads/thread
#define STAGE_B(buf, kt) do {                                               \
    _Pragma("unroll")                                                       \
    for (int j_ = 0; j_ < 2; ++j_) {                                        \
      int li_ = tid + j_ * 512;                                             \
      int row_ = li_ >> 2, slot_ = li_ & 3;                                 \
      int c_ = slot_ ^ ((row_ >> 1) & 3);                                   \
      async16(WbT + (size_t)(col0 + row_) * DD + (kt) * 32 + c_ * 8,        \
              lds + BOFF(buf) + li_ * 8);                                   \
    }                                                                       \
  } while (0)

#define LDA(buf, a) do {                                                    \
    _Pragma("unroll")                                                       \
    for (int mi_ = 0; mi_ < 4; ++mi_) {                                     \
      int r_ = wm * 64 + mi_ * 16 + l15;                                    \
      a[mi_] = *(const s16x8*)(lds + AOFF(buf) + r_ * 32 +                  \
                               ((l16 ^ ((r_ >> 1) & 3)) * 8));              \
    }                                                                       \
  } while (0)

#define LDB2(buf, nb, b) do {                                               \
    _Pragma("unroll")                                                       \
    for (int q_ = 0; q_ < 2; ++q_) {                                        \
      int r_ = wn * 64 + ((nb)*2 + q_) * 16 + l15;                          \
      b[q_] = *(const s16x8*)(lds + BOFF(buf) + r_ * 32 +                   \
                              ((l16 ^ ((r_ >> 1) & 3)) * 8));               \
    }                                                                       \
  } while (0)

#define MM(a, b, nb) do {                                                   \
    __builtin_amdgcn_s_setprio(1);                                          \
    _Pragma("unroll")                                                       \
    for (int mi_ = 0; mi_ < 4; ++mi_) {                                     \
      acc[mi_][(nb)*2] = __builtin_amdgcn_mfma_f32_16x16x32_bf16(           \
          a[mi_], b[0], acc[mi_][(nb)*2], 0, 0, 0);                         \
      acc[mi_][(nb)*2 + 1] = __builtin_amdgcn_mfma_f32_16x16x32_bf16(       \
          a[mi_], b[1], acc[mi_][(nb)*2 + 1], 0, 0, 0);                     \
    }                                                                       \
    __builtin_amdgcn_s_setprio(0);                                          \
  } while (0)

#define BAR() __builtin_amdgcn_s_barrier()
#define VMW1() asm volatile("s_waitcnt vmcnt(1)" ::: "memory")
#define VMW3() asm volatile("s_waitcnt vmcnt(3)" ::: "memory")
#define VMW0() asm volatile("s_waitcnt vmcnt(0)" ::: "memory")

  // prologue: tiles 0,1 -> A0,B0,A1,B1 (1+2+1+2 = 6 loads/thread)
  STAGE_A(0, 0); STAGE_B(0, 0); STAGE_A(1, 1); STAGE_B(1, 1);
  VMW3();   // retire A0,B0 (tile 0 ready); A1,B1 still in flight
  BAR();

  for (int t = 0; t < 30; t += 2) {
    s16x8 a[4], b[2];
    // P0: read A0 + B0 nh0 (tile t); restage B1 <- t+1 (free since prev P3)
    LDA(0, a); LDB2(0, 0, b);
    if (t > 0) STAGE_B(1, t + 1);
    BAR(); MM(a, b, 0); BAR();
    // P1: read B0 nh1; restage A0 <- t+2; wait tile t+1 (A1,B1) landed
    LDB2(0, 1, b);
    STAGE_A(0, t + 2);
    BAR(); MM(a, b, 1); VMW1(); BAR();
    // P2: read A1 + B1 nh0 (tile t+1); restage B0 <- t+2
    LDA(1, a); LDB2(1, 0, b);
    STAGE_B(0, t + 2);
    BAR(); MM(a, b, 0); BAR();
    // P3: read B1 nh1; restage A1 <- t+3; wait tile t+2 (A0,B0) landed
    LDB2(1, 1, b);
    STAGE_A(1, t + 3);
    BAR(); MM(a, b, 1); VMW1(); BAR();
  }

  {  // peeled final iteration t=30 (tiles 30,31; stage only B1 <- 31)
    s16x8 a[4], b[2];
    LDA(0, a); LDB2(0, 0, b);
    STAGE_B(1, 31);
    BAR(); MM(a, b, 0); BAR();
    LDB2(0, 1, b);
    BAR(); MM(a, b, 1); VMW0(); BAR();   // drain: A1,B1 (tile 31) landed
    LDA(1, a); LDB2(1, 0, b);
    BAR(); MM(a, b, 0); BAR();
    LDB2(1, 1, b);
    BAR(); MM(a, b, 1);
  }

  // ---- epilogue ----
  const int mode = *mmode;
  const int lanec = lane & 15, laneq = lane >> 4;
  const int wcol0 = col0 + wn * 64;  // wave spans exactly one 64-col group
  const int b_ = row0 >> 13;         // batch (rows never cross batch)

  if (phase == 1) {
    // K section with fused kv_sum reduction
    const int n = (wcol0 - 1024) >> 6;  // head, uniform per wave
    float pc[4] = {0.f, 0.f, 0.f, 0.f};
#pragma unroll
    for (int mi = 0; mi < 4; ++mi) {
#pragma unroll
      for (int r = 0; r < 4; ++r) {
        const int row = row0 + wm * 64 + mi * 16 + laneq * 4 + r;
        const bool msk = get_mask(maskp, row, mode);
        if (!msk) {
          const float sv = sV[(size_t)row * NH + n];
#pragma unroll
          for (int ni = 0; ni < 4; ++ni) {
            const int col = wcol0 + ni * 16 + lanec;
            float v = acc[mi][ni][r] + bcat[col];
            float phi = v > 0.f ? v + 1.f : __expf(v);
            pc[ni] += phi * sv;
          }
        }
      }
    }
#pragma unroll
    for (int ni = 0; ni < 4; ++ni) {
      pc[ni] += __shfl_xor(pc[ni], 16);
      pc[ni] += __shfl_xor(pc[ni], 32);
    }
    if (laneq == 0) {
#pragma unroll
      for (int ni = 0; ni < 4; ++ni) {
        const int colk = wcol0 - 1024 + ni * 16 + lanec;  // 0..1023
        atomicAdd(&kv[b_ * DD + colk], pc[ni]);
      }
    }
  } else {
    // Q section -> out = phi * kv_sum (finalize fused)
    float kvv[4];
#pragma unroll
    for (int ni = 0; ni < 4; ++ni)
      kvv[ni] = kv[b_ * DD + wcol0 + ni * 16 + lanec];
#pragma unroll
    for (int mi = 0; mi < 4; ++mi) {
#pragma unroll
      for (int r = 0; r < 4; ++r) {
        const int row = row0 + wm * 64 + mi * 16 + laneq * 4 + r;
#pragma unroll
        for (int ni = 0; ni < 4; ++ni) {
          const int col = wcol0 + ni * 16 + lanec;
          float v = acc[mi][ni][r] + bcat[col];
          float phi = v > 0.f ? v + 1.f : __expf(v);
          out[(size_t)row * DD + col] = phi * kvv[ni];
        }
      }
    }
  }
}

extern "C" void kernel_launch(void* const* d_in, const int* in_sizes, int n_in,
                              void* d_out, int out_size, void* d_ws, size_t ws_size,
                              hipStream_t stream) {
  const float* query = (const float*)d_in[0];
  const void* maskp = d_in[1];
  const float* Wq = (const float*)d_in[2];
  const float* bq = (const float*)d_in[3];
  const float* Wk = (const float*)d_in[4];
  const float* bk = (const float*)d_in[5];
  const float* Wv = (const float*)d_in[6];
  const float* bv = (const float*)d_in[7];
  float* out = (float*)d_out;

  char* ws = (char*)d_ws;
  u16* qb = (u16*)ws;            ws += (size_t)MROWS * DD * 2;      // 64 MB
  u16* WbT = (u16*)ws;           ws += (size_t)NWBT * DD * 2;       // ~4.2 MB
  float* sV = (float*)ws;        ws += (size_t)MROWS * NH * 4;      // 2 MB
  float* bcat = (float*)ws;      ws += (size_t)NWBT * 4;
  float* kv = (float*)ws;        ws += (size_t)BB * DD * 4;         // 16 KB
  int* mflag = (int*)ws;         ws += 256;

  // zero kv_sum + mask-mode flag (contiguous in workspace)
  hipMemsetAsync(kv, 0, (size_t)BB * DD * 4 + 256, stream);

  build_wbt<<<dim3(2048 / 32, DD / 32), dim3(32, 8), 0, stream>>>(Wq, Wk, WbT);
  build_aux<<<105, 256, 0, stream>>>(Wv, bq, bk, bv, (const u32*)maskp, WbT, bcat, mflag);
  // fused cvt + sV (barrier-free v3)
  prep_q<<<MROWS / 32, 256, 0, stream>>>(query, WbT, bcat, maskp, mflag, qb, sV);
  // K phase first: kv_sum (fused reduction, no phiK materialization)
  gemm_qkv<<<1024, 512, 0, stream>>>(qb, WbT, bcat, maskp, mflag, sV, kv, out, 1);
  // Q phase: out = phiQ * kv_sum (finalize fused, no phiQ materialization)
  gemm_qkv<<<1024, 512, 0, stream>>>(qb, WbT, bcat, maskp, mflag, sV, kv, out, 0);
}